// Round 7
// baseline (633.496 us; speedup 1.0000x reference)
//
#include <hip/hip_runtime.h>
#include <math.h>

#define Bn  32
#define Cn  1536
#define Tn  2048
#define BNn 128
#define SHIFT 12.0f

typedef __attribute__((ext_vector_type(8))) short bf16x8;
typedef __attribute__((ext_vector_type(4))) float fx4;

// round-to-nearest-even fp32 -> bf16 (as ushort)
__device__ __forceinline__ unsigned int f2bf1(float f) {
    unsigned int u = __float_as_uint(f);
    return (u + 0x7fffu + ((u >> 16) & 1u)) >> 16;
}
__device__ __forceinline__ float fast_tanh(float v) {
    // 1 - 2/(e^{2v}+1); exact at +-inf saturation, ~1e-6 rel err
    return 1.f - 2.f / (__expf(2.f * v) + 1.f);
}

// ---------------------------------------------------------------------------
// Prep: convert W_tdnn / W_attn fp32 -> bf16, and zero the atomic acc planes.
// ---------------------------------------------------------------------------
__global__ void k_prep(const float* __restrict__ W1f, const float* __restrict__ Waf,
                       short* __restrict__ W1b, short* __restrict__ Wab,
                       float* __restrict__ accp) {
    int i = blockIdx.x * 256 + threadIdx.x;
    if (i < BNn * Cn) {
        W1b[i] = (short)f2bf1(W1f[i]);
        Wab[i] = (short)f2bf1(Waf[i]);
    }
    if (i < Bn * Cn)
        *(float4*)&accp[(size_t)i * 4] = make_float4(0.f, 0.f, 0.f, 0.f);
}

// ---------------------------------------------------------------------------
// Stage one 128o x 64k W1 chunk global->LDS (16B granules), ^(o&7) swizzle
// carried on the SOURCE address; LDS dest linear (wave-uniform + lane*16).
// ---------------------------------------------------------------------------
__device__ __forceinline__ void stage_w1(short* sW, const short* __restrict__ W1,
                                         int tid, int k0) {
    #pragma unroll
    for (int j = 0; j < 4; ++j) {
        const int o   = (tid >> 3) + j * 32;
        const int blk = (tid & 7) ^ (o & 7);
        __builtin_amdgcn_global_load_lds(
            (const __attribute__((address_space(1))) unsigned int*)
                (W1 + (size_t)o * Cn + k0 + blk * 8),
            (__attribute__((address_space(3))) unsigned int*)(sW + tid * 8 + j * 2048),
            16, 0, 0);
    }
}

// ---------------------------------------------------------------------------
// Fused kernel. Block = (b, 128-t tile), 256 threads (4 waves, 2x2).
// Phase 1: e-tile = tanh(W1 @ x + b) -> LDS sE (bf16, ^(t&15) swizzle).
//   R7: W1 panels staged to LDS (sE space, double-buffered) via
//   global_load_lds, issued a full compute-phase ahead; compute is pure
//   ds_read+MFMA. Single xr buffer (loads for chunk i+1 issue during
//   compute of chunk i, drain at the next barrier).
// Phase 2: scores via MFMA (A = e-tile regs, B = Wa rows from L2, 2-deep
//   reg pipeline), fixed-shift softmax partials (|a| <= ~11.3), atomicAdd
//   of (S0,S1,S2) into accp planes; k_final computes mean/std.
// ---------------------------------------------------------------------------

#define P1_LOAD(XR, K0) do {                                                  \
    _Pragma("unroll") for (int p = 0; p < 2; ++p) {                           \
        const int c_ = cq + p * 32;                                           \
        _Pragma("unroll") for (int j = 0; j < 4; ++j)                         \
            XR[p][j] = *(const float4*)(xt + (size_t)((K0) + c_ + j) * Tn + t4); \
    }                                                                         \
} while (0)

#define P1_WRITE(XR) do {                                                     \
    _Pragma("unroll") for (int p = 0; p < 2; ++p) {                           \
        const int c_   = cq + p * 32;                                         \
        const int blk_ = c_ >> 3;                                             \
        const int sub_ = c_ & 7;                                              \
        _Pragma("unroll") for (int i2 = 0; i2 < 4; ++i2) {                    \
            const int t_ = t4 + i2;                                           \
            unsigned int lo_ = f2bf1(((const float*)&XR[p][0])[i2]) |         \
                               (f2bf1(((const float*)&XR[p][1])[i2]) << 16);  \
            unsigned int hi_ = f2bf1(((const float*)&XR[p][2])[i2]) |         \
                               (f2bf1(((const float*)&XR[p][3])[i2]) << 16);  \
            const int idx_ = t_ * 64 + ((blk_ ^ (t_ & 7)) << 3) + sub_;       \
            *(uint2*)(sA + idx_) = make_uint2(lo_, hi_);                      \
        }                                                                     \
    }                                                                         \
} while (0)

#define P1_COMPUTE(SW) do {                                                   \
    _Pragma("unroll") for (int kt = 0; kt < 2; ++kt) {                        \
        bf16x8 bq_[4];                                                        \
        _Pragma("unroll") for (int nn = 0; nn < 4; ++nn) {                    \
            const int o_ = wo + nn * 16 + ln;                                 \
            bq_[nn] = *(const bf16x8*)((SW) + o_ * 64                         \
                                       + (((kt * 4 + g) ^ (o_ & 7)) << 3));   \
        }                                                                     \
        bf16x8 af_[4];                                                        \
        _Pragma("unroll") for (int mm = 0; mm < 4; ++mm) {                    \
            const int t_ = wt + mm * 16 + ln;                                 \
            af_[mm] = *(const bf16x8*)(sA + t_ * 64                           \
                                       + (((kt * 4 + g) ^ (t_ & 7)) << 3));   \
        }                                                                     \
        _Pragma("unroll") for (int mm = 0; mm < 4; ++mm)                      \
            _Pragma("unroll") for (int nn = 0; nn < 4; ++nn)                  \
                acc[mm][nn] = __builtin_amdgcn_mfma_f32_16x16x32_bf16(        \
                    af_[mm], bq_[nn], acc[mm][nn], 0, 0, 0);                  \
    }                                                                         \
} while (0)

// phase-2 column-group I in [0,48): c0 descending (L3-hottest first)
#define P2_CR(I) (((Cn - 64) - ((I) >> 1) * 64) + wc + ((I) & 1) * 16 + ln)

#define P2_LOAD(BQ, XQ, I) do {                                               \
    const int cr_ = P2_CR(I);                                                 \
    _Pragma("unroll") for (int kt = 0; kt < 4; ++kt)                          \
        BQ[kt] = *(const bf16x8*)(Wab + (size_t)cr_ * BNn + kt * 32 + g * 8); \
    _Pragma("unroll") for (int mt = 0; mt < 4; ++mt)                          \
        XQ[mt] = *(const float4*)(xb + (size_t)cr_ * Tn                       \
                                  + t0g + wt + mt * 16 + g * 4);              \
} while (0)

#define P2_COMPUTE(BQ, XQ, I) do {                                           \
    fx4 a2_[4];                                                               \
    _Pragma("unroll") for (int mt = 0; mt < 4; ++mt)                          \
        a2_[mt] = (fx4){0.f, 0.f, 0.f, 0.f};                                  \
    _Pragma("unroll") for (int kt = 0; kt < 4; ++kt)                          \
        _Pragma("unroll") for (int mt = 0; mt < 4; ++mt)                      \
            a2_[mt] = __builtin_amdgcn_mfma_f32_16x16x32_bf16(                \
                af2[mt][kt], BQ[kt], a2_[mt], 0, 0, 0);                       \
    float s0_ = 0.f, s1_ = 0.f, s2_ = 0.f;                                    \
    _Pragma("unroll") for (int mt = 0; mt < 4; ++mt) {                        \
        _Pragma("unroll") for (int r = 0; r < 4; ++r) {                       \
            const int msk_ = ((const int*)&mv[mt])[r];                        \
            const float p_ = msk_ ? 0.f : __expf(a2_[mt][r] - SHIFT);         \
            const float xv_ = ((const float*)&XQ[mt])[r];                     \
            s0_ += p_; s1_ += p_ * xv_; s2_ += p_ * xv_ * xv_;                \
        }                                                                     \
    }                                                                         \
    s0_ += __shfl_xor(s0_, 16); s1_ += __shfl_xor(s1_, 16);                   \
    s2_ += __shfl_xor(s2_, 16);                                               \
    s0_ += __shfl_xor(s0_, 32); s1_ += __shfl_xor(s1_, 32);                   \
    s2_ += __shfl_xor(s2_, 32);                                               \
    if (g == 0) {                                                             \
        float* ap_ = accp + ((size_t)b * Cn + P2_CR(I)) * 4;                  \
        atomicAdd(ap_ + 0, s0_);                                              \
        atomicAdd(ap_ + 1, s1_);                                              \
        atomicAdd(ap_ + 2, s2_);                                              \
    }                                                                         \
} while (0)

__global__ __launch_bounds__(256, 2) void k_fused(
    const float* __restrict__ x, const short* __restrict__ W1,
    const float* __restrict__ bias, const short* __restrict__ Wab,
    const int* __restrict__ mask, float* __restrict__ accp)
{
    __shared__ short sA[128 * 64];   // phase-1 x^T staging, ^(t&7) swizzle
    __shared__ short sE[128 * 128];  // phase-1: W1 dbuf (2x16KB); then e-tile

    const int b    = blockIdx.y;
    const int t0g  = blockIdx.x * 128;
    const int tid  = threadIdx.x;
    const int lane = tid & 63;
    const int wv   = tid >> 6;
    const int ln   = lane & 15;
    const int g    = lane >> 4;
    const int wt   = (wv & 1) * 64;   // t-half (both phases)
    const int wo   = (wv >> 1) * 64;  // phase-1 o-half

    const float* xb = x + (size_t)b * Cn * Tn;
    const float* xt = xb + t0g;

    const int t4 = (tid & 31) * 4;
    const int cq = (tid >> 5) * 4;

    short* const sW0 = sE;           // W1 double buffer in sE space
    short* const sW1 = sE + 8192;

    // ---------------- phase 1: e-tile via MFMA over K=C ----------------
    fx4 acc[4][4];
    #pragma unroll
    for (int i = 0; i < 4; ++i)
        #pragma unroll
        for (int j = 0; j < 4; ++j) acc[i][j] = (fx4){0.f, 0.f, 0.f, 0.f};

    float4 xr[2][4];
    stage_w1(sW0, W1, tid, 0);
    P1_LOAD(xr, 0);

    for (int i = 0; i < Cn / 64; ++i) {
        const int k0 = i * 64;
        short* const sWc = (i & 1) ? sW1 : sW0;
        short* const sWn = (i & 1) ? sW0 : sW1;
        __syncthreads();               // stage(sWc) + xr landed; prev reads done
        P1_WRITE(xr);
        __syncthreads();               // sA visible
        if (i + 1 < Cn / 64) {
            stage_w1(sWn, W1, tid, k0 + 64);   // drains at NEXT top barrier
            P1_LOAD(xr, k0 + 64);              // ditto
        }
        P1_COMPUTE(sWc);
    }
    __syncthreads();                   // all sW reads done before sE reuse

    // epilogue: bias + tanh -> sE[t][o], 16B-block swizzle ^(t&15)
    float bs[4];
    #pragma unroll
    for (int nn = 0; nn < 4; ++nn) bs[nn] = bias[wo + nn * 16 + ln];

    #pragma unroll
    for (int mm = 0; mm < 4; ++mm)
        #pragma unroll
        for (int nn = 0; nn < 4; ++nn) {
            #pragma unroll
            for (int r = 0; r < 4; ++r) {
                const int t = wt + mm * 16 + g * 4 + r;
                const int o = wo + nn * 16 + ln;
                const float v = fast_tanh(acc[mm][nn][r] + bs[nn]);
                sE[t * 128 + (((o >> 3) ^ (t & 15)) << 3) + (o & 7)] = (short)f2bf1(v);
            }
        }
    __syncthreads();

    // ---------------- phase 2: scores + stats, 2-deep pipe, no barriers -
    bf16x8 af2[4][4];
    #pragma unroll
    for (int mt = 0; mt < 4; ++mt)
        #pragma unroll
        for (int kt = 0; kt < 4; ++kt) {
            const int t = wt + mt * 16 + ln;
            af2[mt][kt] = *(const bf16x8*)(sE + t * 128 + (((kt * 4 + g) ^ (t & 15)) << 3));
        }

    int4 mv[4];
    #pragma unroll
    for (int mt = 0; mt < 4; ++mt)
        mv[mt] = *(const int4*)(mask + (size_t)b * Tn + t0g + wt + mt * 16 + g * 4);

    const int wc = (wv >> 1) * 32;   // c-half within 64-chunk

    bf16x8 bA[4], bB[4];
    float4 xA[4], xB[4];
    P2_LOAD(bA, xA, 0);
    for (int i = 0; i < 48; i += 2) {
        P2_LOAD(bB, xB, i + 1);              // prefetch next group
        P2_COMPUTE(bA, xA, i);
        if (i + 2 < 48) P2_LOAD(bA, xA, i + 2);
        P2_COMPUTE(bB, xB, i + 1);
    }
}

// ---------------------------------------------------------------------------
// Finalize: acc planes -> mean/std output.
// ---------------------------------------------------------------------------
__global__ void k_final(const float* __restrict__ accp, float* __restrict__ out) {
    const int i = blockIdx.x * 256 + threadIdx.x;
    if (i >= Bn * Cn) return;
    const int b = i / Cn, c = i - b * Cn;
    const float4 v = *(const float4*)&accp[(size_t)i * 4];
    const float mean = v.y / v.x;
    const float var  = fmaxf(v.z / v.x - mean * mean, 1e-9f);
    out[(size_t)b * (2 * Cn) + c]      = mean;
    out[(size_t)b * (2 * Cn) + Cn + c] = sqrtf(var);
}

extern "C" void kernel_launch(void* const* d_in, const int* in_sizes, int n_in,
                              void* d_out, int out_size, void* d_ws, size_t ws_size,
                              hipStream_t stream) {
    const float* x      = (const float*)d_in[0];
    const int*   mask   = (const int*)d_in[1];
    const float* W_tdnn = (const float*)d_in[2];
    const float* b_tdnn = (const float*)d_in[3];
    const float* W_attn = (const float*)d_in[4];
    // d_in[5] = b_attn: constant over t per row -> cancels in softmax. Unused.
    float* out = (float*)d_out;

    short* W1b  = (short*)d_ws;                     // BN*C bf16
    short* Wab  = W1b + (size_t)BNn * Cn;           // C*BN bf16
    float* accp = (float*)(Wab + (size_t)BNn * Cn); // B*C*4 f32 = 786 KB (S0,S1,S2,pad)

    k_prep<<<dim3((BNn * Cn + 255) / 256), 256, 0, stream>>>(W_tdnn, W_attn, W1b, Wab, accp);
    k_fused<<<dim3(Tn / 128, Bn), 256, 0, stream>>>(x, W1b, b_tdnn, Wab, mask, accp);
    k_final<<<dim3((Bn * Cn + 255) / 256), 256, 0, stream>>>(accp, out);
}